// Round 10
// baseline (95.874 us; speedup 1.0000x reference)
//
#include <hip/hip_runtime.h>

// Problem constants (from reference setup_inputs).
#define BATCH  4
#define NQ     8192
#define NA     6890
#define NPAIR  3445   // real anchor pairs per batch
#define NPAD   3456   // padded pairs per batch = 4 quarters x 864
#define QTR    864    // pairs per LDS tile (one anchor quarter)
#define NWAVE  16     // waves per block (1024 threads)
#define PPT    54     // pairs per wave per tile (864/16)
#define QPB    256    // queries per block (4 per thread)
#define NQG    128    // query groups (256 queries each)

typedef float v2f __attribute__((ext_vector_type(2)));

// ---------------------------------------------------------------------------
// Dispatch 1: quarter-split main kernel, QPT=4.
// R9 post-mortem: at QPT=2, LDS reads (23.0 us/CU) slightly outweigh the
// VALU floor (~20 us, invariant). QPT=4 halves LDS again (3456 reads/CU =
// 11.5 us) leaving the kernel purely VALU-bound, while keeping the proven
// 512-block / 2-per-CU / 8-waves-per-SIMD geometry (R7/R9).
//
// Block (qg, quarter): stages anchor-pair tile `quarter` (864 pairs, 27.6 KB,
// packed inline to (x0,x1,y0,y1)(z0,z1,h0,h1), h = 0.5*|a|^2, pads h=1e30),
// scans against its 256 queries (thread -> lane, +64, +128, +192),
// block-reduces to 256 partial argmin keys, PLAIN-stores to pkeys[qtr][gid].
// No fences / device atomics (R8 lesson) — kernel boundary publishes.
// Keys: score = h + hq - q.a = 0.5*||q-a||^2 >= 0 -> float bits order as
// uint; key = (bits & 0xFFFFE000) | idx (idx uniform -> SGPR operand of
// v_and_or_b32); best = v_min3_u32(kA, kB, best).
// Same quantization as rounds 4-9 (absmax 0 throughout).
// ---------------------------------------------------------------------------
__global__ __launch_bounds__(NWAVE * 64, 8)
void collision_split4_kernel(const float* __restrict__ query,
                             const float* __restrict__ anchor,
                             unsigned* __restrict__ pkeys) {   // [4][BATCH*NQ]
    __shared__ union {
        float4   st[QTR * 2];         // 864 pairs x 32 B = 27648 B
        unsigned key[NWAVE][QPB];     // 16 KB overlay for the block reduction
    } sh;

    const int tid  = threadIdx.x;
    const int lane = tid & 63;
    const int wave = __builtin_amdgcn_readfirstlane(tid >> 6);
    const int qg   = blockIdx.x >> 2;          // query group (256 queries)
    const int qtr  = blockIdx.x & 3;           // which anchor quarter
    const int b    = qg >> 5;                  // 32 groups per batch
    const int qbase = (qg & 31) * QPB;

    // Per-thread queries: lane, lane+64, lane+128, lane+192 of the group.
    const float* qp0 = query + ((size_t)b * NQ + qbase + lane) * 3;
    const float* qp1 = qp0 +  64 * 3;
    const float* qp2 = qp0 + 128 * 3;
    const float* qp3 = qp0 + 192 * 3;
    const float q0x = qp0[0], q0y = qp0[1], q0z = qp0[2];
    const float q1x = qp1[0], q1y = qp1[1], q1z = qp1[2];
    const float q2x = qp2[0], q2y = qp2[1], q2z = qp2[2];
    const float q3x = qp3[0], q3y = qp3[1], q3z = qp3[2];
    const v2f nq0x = {-q0x,-q0x}, nq0y = {-q0y,-q0y}, nq0z = {-q0z,-q0z};
    const v2f nq1x = {-q1x,-q1x}, nq1y = {-q1y,-q1y}, nq1z = {-q1z,-q1z};
    const v2f nq2x = {-q2x,-q2x}, nq2y = {-q2y,-q2y}, nq2z = {-q2z,-q2z};
    const v2f nq3x = {-q3x,-q3x}, nq3y = {-q3y,-q3y}, nq3z = {-q3z,-q3z};
    const v2f hq0v = {0.5f*(q0x*q0x+q0y*q0y+q0z*q0z), 0.5f*(q0x*q0x+q0y*q0y+q0z*q0z)};
    const v2f hq1v = {0.5f*(q1x*q1x+q1y*q1y+q1z*q1z), 0.5f*(q1x*q1x+q1y*q1y+q1z*q1z)};
    const v2f hq2v = {0.5f*(q2x*q2x+q2y*q2y+q2z*q2z), 0.5f*(q2x*q2x+q2y*q2y+q2z*q2z)};
    const v2f hq3v = {0.5f*(q3x*q3x+q3y*q3y+q3z*q3z), 0.5f*(q3x*q3x+q3y*q3y+q3z*q3z)};

    const float* __restrict__ Araw = anchor + (size_t)b * NA * 3;

    // ---- stage this block's tile: pairs [qtr*QTR, qtr*QTR+QTR) ----
    for (int p = tid; p < QTR; p += NWAVE * 64) {
        const int gp = qtr * QTR + p;         // pair index in [0, NPAD)
        float4 A, B;
        if (gp < NPAIR) {                     // NA even -> pair fully real
            const float* s = Araw + (size_t)6 * gp;
            const float x0 = s[0], y0 = s[1], z0 = s[2];
            const float x1 = s[3], y1 = s[4], z1 = s[5];
            A = make_float4(x0, x1, y0, y1);
            B = make_float4(z0, z1,
                            0.5f * (x0*x0 + y0*y0 + z0*z0),
                            0.5f * (x1*x1 + y1*y1 + z1*z1));
        } else {                              // sentinel pad: never wins
            A = make_float4(0.f, 0.f, 0.f, 0.f);
            B = make_float4(0.f, 0.f, 1e30f, 1e30f);
        }
        sh.st[2*p]   = A;
        sh.st[2*p+1] = B;
    }
    __syncthreads();

    // ---- compute: this wave's private 54-pair slab, all four queries ----
    const int base = wave * PPT;
    const int k0   = 2 * (qtr * QTR + base);          // global anchor index
    const float4* S = sh.st + (size_t)2 * base;

    unsigned best0 = 0xFFFFFFFFu, best1 = 0xFFFFFFFFu;
    unsigned best2 = 0xFFFFFFFFu, best3 = 0xFFFFFFFFu;

    #pragma unroll 2
    for (int p = 0; p < PPT; ++p) {
        const float4 A  = S[2*p];      // x0,x1,y0,y1  (broadcast ds_read)
        const float4 Bq = S[2*p+1];    // z0,z1,h0,h1
        const v2f X = {A.x,  A.y},  Y = {A.z,  A.w};
        const v2f Z = {Bq.x, Bq.y}, H = {Bq.z, Bq.w};
        const unsigned idx = (unsigned)(k0 + 2*p);    // wave-uniform (SGPR)
        const v2f s0 = __builtin_elementwise_fma(X, nq0x,
                         __builtin_elementwise_fma(Y, nq0y,
                           __builtin_elementwise_fma(Z, nq0z, H + hq0v)));
        const v2f s1 = __builtin_elementwise_fma(X, nq1x,
                         __builtin_elementwise_fma(Y, nq1y,
                           __builtin_elementwise_fma(Z, nq1z, H + hq1v)));
        const v2f s2 = __builtin_elementwise_fma(X, nq2x,
                         __builtin_elementwise_fma(Y, nq2y,
                           __builtin_elementwise_fma(Z, nq2z, H + hq2v)));
        const v2f s3 = __builtin_elementwise_fma(X, nq3x,
                         __builtin_elementwise_fma(Y, nq3y,
                           __builtin_elementwise_fma(Z, nq3z, H + hq3v)));
        unsigned kA, kB, m;
        kA = (__float_as_uint(s0.x) & 0xFFFFE000u) |  idx;
        kB = (__float_as_uint(s0.y) & 0xFFFFE000u) | (idx + 1);
        m = kA < kB ? kA : kB;  best0 = m < best0 ? m : best0;
        kA = (__float_as_uint(s1.x) & 0xFFFFE000u) |  idx;
        kB = (__float_as_uint(s1.y) & 0xFFFFE000u) | (idx + 1);
        m = kA < kB ? kA : kB;  best1 = m < best1 ? m : best1;
        kA = (__float_as_uint(s2.x) & 0xFFFFE000u) |  idx;
        kB = (__float_as_uint(s2.y) & 0xFFFFE000u) | (idx + 1);
        m = kA < kB ? kA : kB;  best2 = m < best2 ? m : best2;
        kA = (__float_as_uint(s3.x) & 0xFFFFE000u) |  idx;
        kB = (__float_as_uint(s3.y) & 0xFFFFE000u) | (idx + 1);
        m = kA < kB ? kA : kB;  best3 = m < best3 ? m : best3;
    }

    __syncthreads();   // slab reads done before overlay write
    sh.key[wave][lane]       = best0;
    sh.key[wave][ 64 + lane] = best1;
    sh.key[wave][128 + lane] = best2;
    sh.key[wave][192 + lane] = best3;
    __syncthreads();

    // ---- block reduction + publish partial (plain store) ----
    if (tid < QPB) {
        unsigned bk = sh.key[0][tid];
        #pragma unroll
        for (int w = 1; w < NWAVE; ++w) {
            const unsigned v = sh.key[w][tid];
            bk = v < bk ? v : bk;
        }
        pkeys[(size_t)qtr * (BATCH * NQ) + (size_t)b * NQ + qbase + tid] = bk;
    }
}

// ---------------------------------------------------------------------------
// Dispatch 2: finalize. Min the four quarter-partials per query, exact
// d2/dot recompute for the winner (identical math to rounds 0-9), ballot +
// one atomic per wave. Kernel boundary publishes dispatch-1 plain stores.
// ---------------------------------------------------------------------------
__global__ void finalize_kernel(const float* __restrict__ query,
                                const float* __restrict__ anchor,
                                const float* __restrict__ normals,
                                const unsigned* __restrict__ pkeys,
                                float* __restrict__ out) {
    const int tid = blockIdx.x * 256 + (int)threadIdx.x;
    const int b  = tid >> 13;           // 8192 queries per batch
    const int qi = tid & 8191;
    const unsigned k0 = pkeys[tid];
    const unsigned k1 = pkeys[(size_t)1 * BATCH * NQ + tid];
    const unsigned k2 = pkeys[(size_t)2 * BATCH * NQ + tid];
    const unsigned k3 = pkeys[(size_t)3 * BATCH * NQ + tid];
    unsigned bk = k0 < k1 ? k0 : k1;
    const unsigned b2 = k2 < k3 ? k2 : k3;
    bk = b2 < bk ? b2 : bk;
    const int bidx = (int)(bk & 8191u);
    const float* qp  = query   + ((size_t)b * NQ + qi)   * 3;
    const float* ap  = anchor  + ((size_t)b * NA + bidx) * 3;
    const float* np2 = normals + ((size_t)b * NA + bidx) * 3;
    const float qx = qp[0], qy = qp[1], qz = qp[2];
    const float dx = qx - ap[0], dy = qy - ap[1], dz = qz - ap[2];
    const float d2  = fmaf(dz, dz, fmaf(dy, dy, dx * dx));
    const float dot = fmaf(dz, np2[2], fmaf(dy, np2[1], dx * np2[0]));
    // dot * (l2 <= 0.5) < 0  <=>  dot < 0 && d2 <= 0.25
    const bool coll = (dot < 0.0f) && (d2 <= 0.25f);
    const unsigned long long m = __ballot(coll);
    if ((threadIdx.x & 63) == 0) atomicAdd(out + b, (float)__popcll(m));
}

// ---------------------------------------------------------------------------
// Fallback (round-7 fused kernel, verbatim) if workspace is too small.
// ---------------------------------------------------------------------------
#define HALF   1728
#define PPTF   108

__global__ __launch_bounds__(NWAVE * 64, 8)
void collision_occ_kernel(const float* __restrict__ query,
                          const float* __restrict__ anchor,
                          const float* __restrict__ normals,
                          float* __restrict__ out) {
    __shared__ union {
        float4   st[HALF * 2];
        unsigned key[NWAVE][64];
    } sh;

    const int tid  = threadIdx.x;
    const int lane = tid & 63;
    const int wave = __builtin_amdgcn_readfirstlane(tid >> 6);
    const int b = blockIdx.x >> 7;
    const int q = (blockIdx.x & 127) * 64 + lane;

    const float* qp = query + ((size_t)b * NQ + q) * 3;
    const float qx = qp[0], qy = qp[1], qz = qp[2];
    const float hq = 0.5f * (qx*qx + qy*qy + qz*qz);
    const v2f nqx = {-qx,-qx}, nqy = {-qy,-qy}, nqz = {-qz,-qz};
    const v2f hqv = {hq, hq};

    const float* __restrict__ Araw = anchor + (size_t)b * NA * 3;

    unsigned best0 = 0xFFFFFFFFu, best1 = 0xFFFFFFFFu;

    #pragma unroll 1
    for (int t = 0; t < 2; ++t) {
        for (int p = tid; p < HALF; p += NWAVE * 64) {
            const int gp = t * HALF + p;
            float4 A, B;
            if (gp < NPAIR) {
                const float* s = Araw + (size_t)6 * gp;
                const float x0 = s[0], y0 = s[1], z0 = s[2];
                const float x1 = s[3], y1 = s[4], z1 = s[5];
                A = make_float4(x0, x1, y0, y1);
                B = make_float4(z0, z1,
                                0.5f * (x0*x0 + y0*y0 + z0*z0),
                                0.5f * (x1*x1 + y1*y1 + z1*z1));
            } else {
                A = make_float4(0.f, 0.f, 0.f, 0.f);
                B = make_float4(0.f, 0.f, 1e30f, 1e30f);
            }
            sh.st[2*p]   = A;
            sh.st[2*p+1] = B;
        }
        __syncthreads();

        const int base = wave * PPTF;
        const int k0   = 2 * (t * HALF + base);
        const float4* S = sh.st + (size_t)2 * base;

        #pragma unroll 4
        for (int p = 0; p < PPTF; ++p) {
            const float4 A  = S[2*p];
            const float4 Bq = S[2*p+1];
            const v2f X = {A.x,  A.y},  Y = {A.z,  A.w};
            const v2f Z = {Bq.x, Bq.y}, H = {Bq.z, Bq.w};
            const unsigned idx = (unsigned)(k0 + 2*p);
            const v2f h = H + hqv;
            const v2f s = __builtin_elementwise_fma(X, nqx,
                            __builtin_elementwise_fma(Y, nqy,
                              __builtin_elementwise_fma(Z, nqz, h)));
            unsigned k;
            k = (__float_as_uint(s.x) & 0xFFFFE000u) |  idx;      best0 = k < best0 ? k : best0;
            k = (__float_as_uint(s.y) & 0xFFFFE000u) | (idx + 1); best1 = k < best1 ? k : best1;
        }
        __syncthreads();
    }

    sh.key[wave][lane] = best1 < best0 ? best1 : best0;
    __syncthreads();

    if (tid < 64) {
        unsigned bk = sh.key[0][lane];
        #pragma unroll
        for (int w = 1; w < NWAVE; ++w) {
            const unsigned v = sh.key[w][lane];
            bk = v < bk ? v : bk;
        }
        const int bidx = (int)(bk & 8191u);
        const float* ap   = Araw + (size_t)bidx * 3;
        const float* npnt = normals + ((size_t)b * NA + bidx) * 3;
        const float dx = qx - ap[0], dy = qy - ap[1], dz = qz - ap[2];
        const float d2  = fmaf(dz, dz, fmaf(dy, dy, dx * dx));
        const float dot = fmaf(dz, npnt[2], fmaf(dy, npnt[1], dx * npnt[0]));
        const bool coll = (dot < 0.0f) && (d2 <= 0.25f);
        const unsigned long long m = __ballot(coll);
        if (lane == 0) atomicAdd(out + b, (float)__popcll(m));
    }
}

extern "C" void kernel_launch(void* const* d_in, const int* in_sizes, int n_in,
                              void* d_out, int out_size, void* d_ws, size_t ws_size,
                              hipStream_t stream) {
    const float* query   = (const float*)d_in[0];
    const float* anchor  = (const float*)d_in[1];
    const float* normals = (const float*)d_in[2];
    float* out = (float*)d_out;

    // d_out is poisoned with 0xAA before every call — zero it (graph-safe).
    hipMemsetAsync(d_out, 0, (size_t)out_size * sizeof(float), stream);

    const size_t PKEY_BYTES = (size_t)4 * BATCH * NQ * sizeof(unsigned); // 512 KB

    if (d_ws && ws_size >= PKEY_BYTES) {
        unsigned* pkeys = (unsigned*)d_ws;
        // No pkeys init needed: every slot is written in dispatch 1 before
        // being read in dispatch 2 (kernel boundary orders + flushes).
        // 512 blocks x 1024 threads: 128 query groups x 4 anchor quarters
        // (2 blocks/CU, 55.3 KB LDS/CU, 32 waves/CU = 8 waves/SIMD).
        collision_split4_kernel<<<dim3(NQG * 4), dim3(NWAVE * 64), 0, stream>>>(
            query, anchor, pkeys);
        finalize_kernel<<<dim3(BATCH * NQ / 256), dim3(256), 0, stream>>>(
            query, anchor, normals, pkeys, out);
    } else {
        collision_occ_kernel<<<dim3(BATCH * (NQ / 64)), dim3(NWAVE * 64), 0, stream>>>(
            query, anchor, normals, out);
    }
}

// Round 11
// 94.968 us; speedup vs baseline: 1.0095x; 1.0095x over previous
//
#include <hip/hip_runtime.h>

// Problem constants (from reference setup_inputs).
#define BATCH  4
#define NQ     8192
#define NA     6890
#define NPAIR  3445   // real anchor pairs per batch
#define NPAD   3456   // padded pairs per batch = 4 quarters x 864
#define QTR    864    // pairs per LDS tile (one anchor quarter)
#define NWAVE  16     // waves per block (1024 threads)
#define PPT    54     // pairs per wave per tile (864/16), even
#define QPB    256    // queries per block (4 per thread)
#define NQG    128    // query groups (256 queries each)

typedef float v2f __attribute__((ext_vector_type(2)));

// ---------------------------------------------------------------------------
// Dispatch 1: quarter-split main kernel, QPT=4 (R10 geometry: 512 blocks,
// 2/CU, 8 waves/SIMD) with register-pressure relief:
//  - query constants kept as SCALARS, splatted (v2f){s,s} at use so the
//    VOP3P op_sel path reads one VGPR for both halves (32 -> 16 VGPRs of
//    loop-invariant state under the 64-VGPR launch_bounds cap);
//  - explicit 2-pair loop body (4 ds_reads up front, then pure VALU);
//  - out[] zeroed here (blocks 0/128/256/384) -> no memset dispatch.
// Keys: score = h + hq - q.a = 0.5*||q-a||^2 >= 0 -> float bits order as
// uint; key = (bits & 0xFFFFE000) | idx (idx wave-uniform SGPR; mask hoisted
// to VGPR -> v_and_or_b32); best = min3(kA, kB, best).
// Plain stores publish partials; kernel boundary (not fences) orders them
// (R8 lesson). Same quantization as rounds 4-10 (absmax 0 throughout).
// ---------------------------------------------------------------------------
#define EVP(Af, Bf, KS, nx, ny, nz, hqs, best) do {                          \
    const v2f _X = {(Af).x, (Af).y}, _Y = {(Af).z, (Af).w};                  \
    const v2f _Z = {(Bf).x, (Bf).y}, _H = {(Bf).z, (Bf).w};                  \
    const v2f _s = __builtin_elementwise_fma(_X, (v2f){(nx),(nx)},           \
                     __builtin_elementwise_fma(_Y, (v2f){(ny),(ny)},         \
                       __builtin_elementwise_fma(_Z, (v2f){(nz),(nz)},       \
                         _H + (v2f){(hqs),(hqs)})));                         \
    const unsigned _kA = (__float_as_uint(_s.x) & 0xFFFFE000u) |  (KS);      \
    const unsigned _kB = (__float_as_uint(_s.y) & 0xFFFFE000u) | ((KS) + 1); \
    const unsigned _m  = _kA < _kB ? _kA : _kB;                              \
    (best) = _m < (best) ? _m : (best);                                      \
} while (0)

#define EVP_PAIR(Af, Bf, KS) do {                  \
    EVP(Af, Bf, KS, n0x, n0y, n0z, hq0, best0);    \
    EVP(Af, Bf, KS, n1x, n1y, n1z, hq1, best1);    \
    EVP(Af, Bf, KS, n2x, n2y, n2z, hq2, best2);    \
    EVP(Af, Bf, KS, n3x, n3y, n3z, hq3, best3);    \
} while (0)

__global__ __launch_bounds__(NWAVE * 64, 8)
void collision_split4_kernel(const float* __restrict__ query,
                             const float* __restrict__ anchor,
                             unsigned* __restrict__ pkeys,     // [4][BATCH*NQ]
                             float* __restrict__ out) {
    __shared__ union {
        float4   st[QTR * 2];         // 864 pairs x 32 B = 27648 B
        unsigned key[NWAVE][QPB];     // 16 KB overlay for the block reduction
    } sh;

    const int tid  = threadIdx.x;
    const int lane = tid & 63;
    const int wave = __builtin_amdgcn_readfirstlane(tid >> 6);
    const int qg   = blockIdx.x >> 2;          // query group (256 queries)
    const int qtr  = blockIdx.x & 3;           // which anchor quarter
    const int b    = qg >> 5;                  // 32 groups per batch
    const int qbase = (qg & 31) * QPB;

    // Zero the 4-float output from dispatch 1 (replaces the memset dispatch;
    // kernel boundary orders these stores before finalize's atomics).
    if (tid == 0 && (blockIdx.x & 127) == 0) out[blockIdx.x >> 7] = 0.0f;

    // Per-thread queries: lane, lane+64, lane+128, lane+192. All constants
    // kept scalar; splatted at use (VOP3P op_sel) to halve VGPR footprint.
    const float* qp0 = query + ((size_t)b * NQ + qbase + lane) * 3;
    const float* qp1 = qp0 +  64 * 3;
    const float* qp2 = qp0 + 128 * 3;
    const float* qp3 = qp0 + 192 * 3;
    const float n0x = -qp0[0], n0y = -qp0[1], n0z = -qp0[2];
    const float n1x = -qp1[0], n1y = -qp1[1], n1z = -qp1[2];
    const float n2x = -qp2[0], n2y = -qp2[1], n2z = -qp2[2];
    const float n3x = -qp3[0], n3y = -qp3[1], n3z = -qp3[2];
    const float hq0 = 0.5f * (n0x*n0x + n0y*n0y + n0z*n0z);
    const float hq1 = 0.5f * (n1x*n1x + n1y*n1y + n1z*n1z);
    const float hq2 = 0.5f * (n2x*n2x + n2y*n2y + n2z*n2z);
    const float hq3 = 0.5f * (n3x*n3x + n3y*n3y + n3z*n3z);

    const float* __restrict__ Araw = anchor + (size_t)b * NA * 3;

    // ---- stage this block's tile: pairs [qtr*QTR, qtr*QTR+QTR) ----
    for (int p = tid; p < QTR; p += NWAVE * 64) {
        const int gp = qtr * QTR + p;         // pair index in [0, NPAD)
        float4 A, B;
        if (gp < NPAIR) {                     // NA even -> pair fully real
            const float* s = Araw + (size_t)6 * gp;
            const float x0 = s[0], y0 = s[1], z0 = s[2];
            const float x1 = s[3], y1 = s[4], z1 = s[5];
            A = make_float4(x0, x1, y0, y1);
            B = make_float4(z0, z1,
                            0.5f * (x0*x0 + y0*y0 + z0*z0),
                            0.5f * (x1*x1 + y1*y1 + z1*z1));
        } else {                              // sentinel pad: never wins
            A = make_float4(0.f, 0.f, 0.f, 0.f);
            B = make_float4(0.f, 0.f, 1e30f, 1e30f);
        }
        sh.st[2*p]   = A;
        sh.st[2*p+1] = B;
    }
    __syncthreads();

    // ---- compute: this wave's private 54-pair slab, all four queries ----
    const int base = wave * PPT;
    const int k0   = 2 * (qtr * QTR + base);          // global anchor index
    const float4* S = sh.st + (size_t)2 * base;

    unsigned best0 = 0xFFFFFFFFu, best1 = 0xFFFFFFFFu;
    unsigned best2 = 0xFFFFFFFFu, best3 = 0xFFFFFFFFu;

    #pragma unroll 1
    for (int p = 0; p < PPT; p += 2) {        // 2 pairs (4 anchors) per trip
        const float4 A0 = S[2*p],   B0 = S[2*p+1];
        const float4 A1 = S[2*p+2], B1 = S[2*p+3];
        const unsigned i0 = (unsigned)(k0 + 2*p);     // wave-uniform (SGPR)
        EVP_PAIR(A0, B0, i0);
        EVP_PAIR(A1, B1, i0 + 2);
    }

    __syncthreads();   // slab reads done before overlay write
    sh.key[wave][lane]       = best0;
    sh.key[wave][ 64 + lane] = best1;
    sh.key[wave][128 + lane] = best2;
    sh.key[wave][192 + lane] = best3;
    __syncthreads();

    // ---- block reduction + publish partial (plain store) ----
    if (tid < QPB) {
        unsigned bk = sh.key[0][tid];
        #pragma unroll
        for (int w = 1; w < NWAVE; ++w) {
            const unsigned v = sh.key[w][tid];
            bk = v < bk ? v : bk;
        }
        pkeys[(size_t)qtr * (BATCH * NQ) + (size_t)b * NQ + qbase + tid] = bk;
    }
}

// ---------------------------------------------------------------------------
// Dispatch 2: finalize. Min the four quarter-partials per query, exact
// d2/dot recompute for the winner (identical math to rounds 0-10), ballot +
// one atomic per wave. Kernel boundary publishes dispatch-1 plain stores.
// ---------------------------------------------------------------------------
__global__ void finalize_kernel(const float* __restrict__ query,
                                const float* __restrict__ anchor,
                                const float* __restrict__ normals,
                                const unsigned* __restrict__ pkeys,
                                float* __restrict__ out) {
    const int tid = blockIdx.x * 256 + (int)threadIdx.x;
    const int b  = tid >> 13;           // 8192 queries per batch
    const int qi = tid & 8191;
    const unsigned k0 = pkeys[tid];
    const unsigned k1 = pkeys[(size_t)1 * BATCH * NQ + tid];
    const unsigned k2 = pkeys[(size_t)2 * BATCH * NQ + tid];
    const unsigned k3 = pkeys[(size_t)3 * BATCH * NQ + tid];
    unsigned bk = k0 < k1 ? k0 : k1;
    const unsigned b2 = k2 < k3 ? k2 : k3;
    bk = b2 < bk ? b2 : bk;
    const int bidx = (int)(bk & 8191u);
    const float* qp  = query   + ((size_t)b * NQ + qi)   * 3;
    const float* ap  = anchor  + ((size_t)b * NA + bidx) * 3;
    const float* np2 = normals + ((size_t)b * NA + bidx) * 3;
    const float qx = qp[0], qy = qp[1], qz = qp[2];
    const float dx = qx - ap[0], dy = qy - ap[1], dz = qz - ap[2];
    const float d2  = fmaf(dz, dz, fmaf(dy, dy, dx * dx));
    const float dot = fmaf(dz, np2[2], fmaf(dy, np2[1], dx * np2[0]));
    // dot * (l2 <= 0.5) < 0  <=>  dot < 0 && d2 <= 0.25
    const bool coll = (dot < 0.0f) && (d2 <= 0.25f);
    const unsigned long long m = __ballot(coll);
    if ((threadIdx.x & 63) == 0) atomicAdd(out + b, (float)__popcll(m));
}

// ---------------------------------------------------------------------------
// Fallback (round-7 fused kernel, verbatim) if workspace is too small.
// ---------------------------------------------------------------------------
#define HALF   1728
#define PPTF   108

__global__ __launch_bounds__(NWAVE * 64, 8)
void collision_occ_kernel(const float* __restrict__ query,
                          const float* __restrict__ anchor,
                          const float* __restrict__ normals,
                          float* __restrict__ out) {
    __shared__ union {
        float4   st[HALF * 2];
        unsigned key[NWAVE][64];
    } sh;

    const int tid  = threadIdx.x;
    const int lane = tid & 63;
    const int wave = __builtin_amdgcn_readfirstlane(tid >> 6);
    const int b = blockIdx.x >> 7;
    const int q = (blockIdx.x & 127) * 64 + lane;

    const float* qp = query + ((size_t)b * NQ + q) * 3;
    const float qx = qp[0], qy = qp[1], qz = qp[2];
    const float hq = 0.5f * (qx*qx + qy*qy + qz*qz);
    const v2f nqx = {-qx,-qx}, nqy = {-qy,-qy}, nqz = {-qz,-qz};
    const v2f hqv = {hq, hq};

    const float* __restrict__ Araw = anchor + (size_t)b * NA * 3;

    unsigned best0 = 0xFFFFFFFFu, best1 = 0xFFFFFFFFu;

    #pragma unroll 1
    for (int t = 0; t < 2; ++t) {
        for (int p = tid; p < HALF; p += NWAVE * 64) {
            const int gp = t * HALF + p;
            float4 A, B;
            if (gp < NPAIR) {
                const float* s = Araw + (size_t)6 * gp;
                const float x0 = s[0], y0 = s[1], z0 = s[2];
                const float x1 = s[3], y1 = s[4], z1 = s[5];
                A = make_float4(x0, x1, y0, y1);
                B = make_float4(z0, z1,
                                0.5f * (x0*x0 + y0*y0 + z0*z0),
                                0.5f * (x1*x1 + y1*y1 + z1*z1));
            } else {
                A = make_float4(0.f, 0.f, 0.f, 0.f);
                B = make_float4(0.f, 0.f, 1e30f, 1e30f);
            }
            sh.st[2*p]   = A;
            sh.st[2*p+1] = B;
        }
        __syncthreads();

        const int base = wave * PPTF;
        const int k0   = 2 * (t * HALF + base);
        const float4* S = sh.st + (size_t)2 * base;

        #pragma unroll 4
        for (int p = 0; p < PPTF; ++p) {
            const float4 A  = S[2*p];
            const float4 Bq = S[2*p+1];
            const v2f X = {A.x,  A.y},  Y = {A.z,  A.w};
            const v2f Z = {Bq.x, Bq.y}, H = {Bq.z, Bq.w};
            const unsigned idx = (unsigned)(k0 + 2*p);
            const v2f h = H + hqv;
            const v2f s = __builtin_elementwise_fma(X, nqx,
                            __builtin_elementwise_fma(Y, nqy,
                              __builtin_elementwise_fma(Z, nqz, h)));
            unsigned k;
            k = (__float_as_uint(s.x) & 0xFFFFE000u) |  idx;      best0 = k < best0 ? k : best0;
            k = (__float_as_uint(s.y) & 0xFFFFE000u) | (idx + 1); best1 = k < best1 ? k : best1;
        }
        __syncthreads();
    }

    sh.key[wave][lane] = best1 < best0 ? best1 : best0;
    __syncthreads();

    if (tid < 64) {
        unsigned bk = sh.key[0][lane];
        #pragma unroll
        for (int w = 1; w < NWAVE; ++w) {
            const unsigned v = sh.key[w][lane];
            bk = v < bk ? v : bk;
        }
        const int bidx = (int)(bk & 8191u);
        const float* ap   = Araw + (size_t)bidx * 3;
        const float* npnt = normals + ((size_t)b * NA + bidx) * 3;
        const float dx = qx - ap[0], dy = qy - ap[1], dz = qz - ap[2];
        const float d2  = fmaf(dz, dz, fmaf(dy, dy, dx * dx));
        const float dot = fmaf(dz, npnt[2], fmaf(dy, npnt[1], dx * npnt[0]));
        const bool coll = (dot < 0.0f) && (d2 <= 0.25f);
        const unsigned long long m = __ballot(coll);
        if (lane == 0) atomicAdd(out + b, (float)__popcll(m));
    }
}

extern "C" void kernel_launch(void* const* d_in, const int* in_sizes, int n_in,
                              void* d_out, int out_size, void* d_ws, size_t ws_size,
                              hipStream_t stream) {
    const float* query   = (const float*)d_in[0];
    const float* anchor  = (const float*)d_in[1];
    const float* normals = (const float*)d_in[2];
    float* out = (float*)d_out;

    const size_t PKEY_BYTES = (size_t)4 * BATCH * NQ * sizeof(unsigned); // 512 KB

    if (d_ws && ws_size >= PKEY_BYTES) {
        unsigned* pkeys = (unsigned*)d_ws;
        // Exactly 2 dispatches: split (also zeroes out[]) then finalize.
        // No pkeys init needed: every slot is written in dispatch 1 before
        // being read in dispatch 2 (kernel boundary orders + flushes).
        collision_split4_kernel<<<dim3(NQG * 4), dim3(NWAVE * 64), 0, stream>>>(
            query, anchor, pkeys, out);
        finalize_kernel<<<dim3(BATCH * NQ / 256), dim3(256), 0, stream>>>(
            query, anchor, normals, pkeys, out);
    } else {
        // d_out is poisoned with 0xAA before every call — zero it (graph-safe).
        hipMemsetAsync(d_out, 0, (size_t)out_size * sizeof(float), stream);
        collision_occ_kernel<<<dim3(BATCH * (NQ / 64)), dim3(NWAVE * 64), 0, stream>>>(
            query, anchor, normals, out);
    }
}